// Round 6
// baseline (305.649 us; speedup 1.0000x reference)
//
#include <hip/hip_runtime.h>

// Multires hash-grid encode (2D, instant-NGP style). Round 9 (= round 8
// resubmitted verbatim: the round-8 bench died to an infra "container
// failed twice" error before compiling/running anything).
//
// Round-7 evidence: fused-with-deep-MLP lost XCD table affinity -> 690 MiB
// of L2-miss line traffic (21M random 8-B gathers x 64-B lines, ~10% L2 hit)
// served at ~3.7 TB/s fabric ceiling = 210 us. But the fusion structure wins
// were real (x read once, no 128-MiB ws round-trip, WRITE exactly 64 MiB).
//
// This round keeps fusion and restores affinity TEMPORALLY: tables are
// read-only, so if the whole chip works on hashed level l in the same time
// window, that single 4.19-MiB table (== one XCD L2) replicates into all 8
// L2s and stays hot. Mechanisms:
//  (a) hashed levels processed strictly one-at-a-time with a per-level
//      __syncthreads() (waves phase-locked in-block; chip-wide alignment is
//      statistical: identical uniform work, all blocks co-resident).
//  (b) NO LDS: after the level loop, thread t holds point n's entire
//      32-float row in registers -> 8 direct nt float4 stores (a wave's 8
//      stores fully cover 64 consecutive 128-B lines). Zero LDS + low VGPR
//      -> all 2048 blocks co-resident, no late generations to break lockstep.
// Expected FETCH floor ~ 10 levels x 8 XCDs x 4.19 MiB ~ 335 MiB.
// Index math bit-exact vs the jax reference (32-bit residue proof below).

static constexpr int  kPoints    = 524288;
static constexpr int  kLevels    = 16;
static constexpr int  kStartHash = 6;
static constexpr unsigned kPs1     = 19349663u;
static constexpr unsigned kEntries = 524309u;
static constexpr unsigned kR32     = 352277u;   // 2^32 mod kEntries

typedef float v4f __attribute__((ext_vector_type(4)));

__device__ __forceinline__ void nt_store4(float4* p, const float4 v) {
    v4f t; t.x = v.x; t.y = v.y; t.z = v.z; t.w = v.w;
    __builtin_nontemporal_store(t, (v4f*)p);
}

__constant__ unsigned c_level_off[kLevels] = {
    0u, 289u, 1378u, 5603u, 22244u, 88293u, 351462u,
    875771u, 1400080u, 1924389u, 2448698u, 2973007u,
    3497316u, 4021625u, 4545934u, 5070243u
};

struct Corners {
    float    w00, w01, w10, w11;
    unsigned i00, i01, i10, i11;   // absolute table indices (level base folded in)
};

__device__ __forceinline__ Corners prep_level(const float2 p, const int l)
{
    const int   scale_i = 16 << l;
    const float scale_f = (float)scale_i;

    const float fx = p.x * scale_f;
    const float fy = p.y * scale_f;

    // coords in [0,1) -> indices nonnegative, max 524288 at level 15: u32 ok.
    const unsigned ix0 = (unsigned)(int)fx;
    const unsigned iy0 = (unsigned)(int)fy;
    const unsigned ix1 = (unsigned)(int)(fx + 1.0f);   // NOT always ix0+1 (fp rounding)
    const unsigned iy1 = (unsigned)(int)(fy + 1.0f);

    const float ox = fx - (float)ix0;
    const float oy = fy - (float)iy0;

    const float wx1 = fminf(fmaxf(ox, 0.0f), 1.0f);
    const float wx0 = fminf(fmaxf(1.0f - ox, 0.0f), 1.0f);
    const float wy1 = fminf(fmaxf(oy, 0.0f), 1.0f);
    const float wy0 = fminf(fmaxf(1.0f - oy, 0.0f), 1.0f);

    unsigned i00, i01, i10, i11;
    if (l < kStartHash) {
        const unsigned stride = (unsigned)(scale_i + 1);
        i00 = ix0 * stride + iy0;
        i01 = ix0 * stride + iy1;
        i10 = ix1 * stride + iy0;
        i11 = ix1 * stride + iy1;
    } else {
        // 32-bit replication of ((ix ^ (iy*PS1)) % E), bit-exact vs int64:
        // hy = iy*PS1 = hi*2^32+lo, hi <= 2362, ix < 2^20 so xor touches lo only.
        // (hi*2^32 + (lo^ix)) % E = ((hi*R32)%E + (lo^ix)%E) cond-sub E.
        const unsigned long long hy0 = (unsigned long long)iy0 * kPs1;
        const unsigned long long hy1 = (unsigned long long)iy1 * kPs1;
        const unsigned lo0 = (unsigned)hy0, hi0 = (unsigned)(hy0 >> 32);
        const unsigned lo1 = (unsigned)hy1, hi1 = (unsigned)(hy1 >> 32);
        const unsigned a0 = (hi0 * kR32) % kEntries;   // hi*R32 < 2^30
        const unsigned a1 = (hi1 * kR32) % kEntries;
        i00 = a0 + ((lo0 ^ ix0) % kEntries); if (i00 >= kEntries) i00 -= kEntries;
        i01 = a1 + ((lo1 ^ ix0) % kEntries); if (i01 >= kEntries) i01 -= kEntries;
        i10 = a0 + ((lo0 ^ ix1) % kEntries); if (i10 >= kEntries) i10 -= kEntries;
        i11 = a1 + ((lo1 ^ ix1) % kEntries); if (i11 >= kEntries) i11 -= kEntries;
    }

    Corners c;
    const unsigned base = c_level_off[l];
    c.i00 = base + i00; c.i01 = base + i01;
    c.i10 = base + i10; c.i11 = base + i11;
    c.w00 = wx0 * wy0;  c.w01 = wx0 * wy1;
    c.w10 = wx1 * wy0;  c.w11 = wx1 * wy1;
    return c;
}

__device__ __forceinline__ float2 finish_level(
    const Corners& c, const float2* __restrict__ tbl)
{
    const float2 v00 = tbl[c.i00];
    const float2 v01 = tbl[c.i01];
    const float2 v10 = tbl[c.i10];
    const float2 v11 = tbl[c.i11];
    return make_float2(
        c.w00 * v00.x + c.w01 * v01.x + c.w10 * v10.x + c.w11 * v11.x,
        c.w00 * v00.y + c.w01 * v01.y + c.w10 * v10.y + c.w11 * v11.y);
}

// ---- Fused, level-lockstep, no LDS --------------------------------------
__global__ __launch_bounds__(256) void fused_pass(
    const float2* __restrict__ x,
    const float2* __restrict__ tbl,
    float4* __restrict__ out)
{
    const int t = threadIdx.x;
    const int n = (blockIdx.x << 8) | t;
    const float2 p = x[n];          // x read exactly once per point

    float2 r[kLevels];              // statically indexed only -> registers

    // Dense levels 0..5: tables sum 2.8 MiB, resident in every L2. Free-run
    // with full cross-level MLP (24 gathers in flight), no barriers.
#pragma unroll
    for (int l = 0; l < kStartHash; ++l)
        r[l] = finish_level(prep_level(p, l), tbl);

    // Hashed levels 6..15: ONE 4.19-MiB table per level ~= one XCD L2.
    // Strictly one level per time window, barrier-separated, so the live
    // table replicates into all 8 L2s and random gathers become L2 hits.
#pragma unroll
    for (int l = kStartHash; l < kLevels; ++l) {
        __syncthreads();            // phase-lock the block's 4 waves per level
        r[l] = finish_level(prep_level(p, l), tbl);
    }

    // Thread t holds point n's entire 32-float output row: store directly.
    // Per-instruction lanes hit 64 distinct 128-B lines, but the 8 stores
    // together cover 64 consecutive full lines back-to-back; nt keeps the
    // 64-MiB burst out of L2 so it can't evict the live table.
    float4* o = out + (size_t)n * 8;
#pragma unroll
    for (int i = 0; i < 8; ++i)
        nt_store4(&o[i], make_float4(r[2 * i].x,     r[2 * i].y,
                                     r[2 * i + 1].x, r[2 * i + 1].y));
}

extern "C" void kernel_launch(void* const* d_in, const int* in_sizes, int n_in,
                              void* d_out, int out_size, void* d_ws, size_t ws_size,
                              hipStream_t stream) {
    const float2* x   = (const float2*)d_in[0];
    const float2* tbl = (const float2*)d_in[1];
    fused_pass<<<kPoints / 256, 256, 0, stream>>>(x, tbl, (float4*)d_out);
}